// Round 1
// 1033.974 us; speedup vs baseline: 1.1013x; 1.1013x over previous
//
#include <hip/hip_runtime.h>
#include <stdint.h>

#define T_TOKENS 8192
#define DDIM 1024
#define FDIM 3584
#define NEXP 8

#define MAXT1 72    // 256-row tiles: 16384/256 + 8
#define MAXT2 136   // 128-row tiles: 16384/128 + 8

typedef _Float16 f16x8 __attribute__((ext_vector_type(8)));
typedef float f32x4 __attribute__((ext_vector_type(4)));

__device__ __forceinline__ void gload16(const void* g, void* l) {
  __builtin_amdgcn_global_load_lds(
      (const __attribute__((address_space(1))) void*)g,
      (__attribute__((address_space(3))) void*)l, 16, 0, 0);
}

// ---------------- router: logits, softmax, top-2, expert lists; also emits xh=f16(x) ----
__global__ __launch_bounds__(256) void router_kernel(
    const float* __restrict__ x, const float* __restrict__ gw,
    float* __restrict__ logits_out, int* __restrict__ counts,
    int* __restrict__ tok_idx, float* __restrict__ tok_w,
    int2* __restrict__ tok_ref, _Float16* __restrict__ xh) {
  int t = blockIdx.x * 4 + (threadIdx.x >> 6);  // one wave per token
  int lane = threadIdx.x & 63;
  const float* xr = x + (size_t)t * DDIM;
  float acc[NEXP];
#pragma unroll
  for (int e = 0; e < NEXP; e++) acc[e] = 0.f;
  for (int c = 0; c < DDIM / 64; c++) {
    float xv = xr[c * 64 + lane];
    xh[(size_t)t * DDIM + c * 64 + lane] = (_Float16)xv;
#pragma unroll
    for (int e = 0; e < NEXP; e++) acc[e] += xv * gw[e * DDIM + c * 64 + lane];
  }
#pragma unroll
  for (int e = 0; e < NEXP; e++) {
    for (int off = 32; off > 0; off >>= 1) acc[e] += __shfl_xor(acc[e], off, 64);
  }
  if (lane == 0) {
    float m = acc[0];
    for (int e = 1; e < NEXP; e++) m = fmaxf(m, acc[e]);
    float p[NEXP];
    for (int e = 0; e < NEXP; e++) p[e] = expf(acc[e] - m);
    int e1 = 0;
    for (int e = 1; e < NEXP; e++) if (p[e] > p[e1]) e1 = e;  // strict > : lowest idx on tie
    int e2 = (e1 == 0) ? 1 : 0;
    for (int e = 0; e < NEXP; e++) { if (e == e1) continue; if (p[e] > p[e2]) e2 = e; }
    float wsum = p[e1] + p[e2];
    float w1v = p[e1] / wsum, w2v = p[e2] / wsum;
    for (int e = 0; e < NEXP; e++) logits_out[(size_t)t * NEXP + e] = acc[e];
    int pos1 = atomicAdd(&counts[e1], 1);
    tok_idx[e1 * T_TOKENS + pos1] = t; tok_w[e1 * T_TOKENS + pos1] = w1v;
    int pos2 = atomicAdd(&counts[e2], 1);
    tok_idx[e2 * T_TOKENS + pos2] = t; tok_w[e2 * T_TOKENS + pos2] = w2v;
    tok_ref[t] = make_int2((e1 << 13) | pos1, (e2 << 13) | pos2);
  }
}

// ---------------- prefix + compact tile schedules (256-row for gemm1, 128-row for gemm2) ----
__global__ void prefix_kernel(const int* __restrict__ counts, int* __restrict__ offsets,
                              int* __restrict__ sched1, int* __restrict__ sched2) {
  if (threadIdx.x == 0) {
    int s = 0, n1 = 0, n2 = 0;
    for (int e = 0; e < NEXP; e++) {
      offsets[e] = s;
      int cc = counts[e];
      int nt1 = (cc + 255) / 256;
      for (int i = 0; i < nt1; i++) sched1[n1++] = (e << 16) | i;
      int nt2 = (cc + 127) / 128;
      for (int i = 0; i < nt2; i++) sched2[n2++] = (e << 16) | i;
      s += cc;
    }
    offsets[NEXP] = s;
    for (; n1 < MAXT1; n1++) sched1[n1] = -1;
    for (; n2 < MAXT2; n2++) sched2[n2] = -1;
  }
}

// ---------------- transpose+convert: in[e][R][C] fp32 -> out[e][C][R] f16 ----------------
__global__ __launch_bounds__(256) void transpose_f16_kernel(
    const float* __restrict__ in, _Float16* __restrict__ out, int R, int C) {
  __shared__ _Float16 lt[64][72];
  size_t esz = (size_t)R * C;
  in += (size_t)blockIdx.z * esz;
  out += (size_t)blockIdx.z * esz;
  int r0 = blockIdx.y * 64, c0 = blockIdx.x * 64;
  int t = threadIdx.x;
  int r = t & 63, q = t >> 6;
  const float* src = in + (size_t)(r0 + r) * C + c0 + q * 16;
  float4 v0 = ((const float4*)src)[0];
  float4 v1 = ((const float4*)src)[1];
  float4 v2 = ((const float4*)src)[2];
  float4 v3 = ((const float4*)src)[3];
  _Float16 f[16] = {
      (_Float16)v0.x, (_Float16)v0.y, (_Float16)v0.z, (_Float16)v0.w,
      (_Float16)v1.x, (_Float16)v1.y, (_Float16)v1.z, (_Float16)v1.w,
      (_Float16)v2.x, (_Float16)v2.y, (_Float16)v2.z, (_Float16)v2.w,
      (_Float16)v3.x, (_Float16)v3.y, (_Float16)v3.z, (_Float16)v3.w};
#pragma unroll
  for (int j = 0; j < 16; j++) lt[q * 16 + j][r] = f[j];
  __syncthreads();
  _Float16* dst = out + (size_t)(c0 + r) * R + r0 + q * 16;
  *(f16x8*)dst       = *(const f16x8*)&lt[r][q * 16];
  *(f16x8*)(dst + 8) = *(const f16x8*)&lt[r][q * 16 + 8];
}

// ---------------- GEMM1: h = silu(x@w1) * (x@w3), gathered rows ----------------
// Tile 256 rows x 128 cols (both w1 and w3). 512 threads = 8 waves (4M x 2N),
// wave owns 64x64 of BOTH matrices. Counted-vmcnt double-buffer pipeline:
// loads for tile t+2 issued at end of iter t; vmcnt(8) (= next tile's loads
// left in flight) before each compute; raw s_barrier, no vmcnt(0) drain.
__global__ __launch_bounds__(512, 2) void gemm1_kernel(
    const _Float16* __restrict__ xh, const _Float16* __restrict__ w1t,
    const _Float16* __restrict__ w3t, const int* __restrict__ counts,
    const int* __restrict__ offsets, const int* __restrict__ tok_idx,
    const int* __restrict__ sched, _Float16* __restrict__ h) {
  int sc = sched[blockIdx.y];
  if (sc < 0) return;
  int e = sc >> 16, rt = sc & 0xFFFF;
  int cnt = counts[e];
  int ct = blockIdx.x;
  int off = offsets[e];

  // per buffer: A 256x64 (16384 f16) | B1 128x64 (8192) | B3 128x64 (8192)
  __shared__ _Float16 lds[2][32768];

  int tid = threadIdx.x, lane = tid & 63, wv = tid >> 6;
  int p = lane & 7, rsub = lane >> 3, c = p ^ rsub;  // XOR-chunk swizzle (conflict-free, measured)

  const _Float16* aSrc[4];
#pragma unroll
  for (int g = 0; g < 4; g++) {
    int r = wv * 32 + g * 8 + rsub;
    int ir = rt * 256 + r;
    if (ir >= cnt) ir = cnt - 1;
    int tok = tok_idx[e * T_TOKENS + ir];
    aSrc[g] = xh + (size_t)tok * DDIM + c * 8;
  }
  const _Float16 *b1Src[2], *b3Src[2];
#pragma unroll
  for (int g = 0; g < 2; g++) {
    int n = wv * 16 + g * 8 + rsub;
    size_t row = (size_t)e * FDIM + (size_t)ct * 128 + n;
    b1Src[g] = w1t + row * DDIM + c * 8;
    b3Src[g] = w3t + row * DDIM + c * 8;
  }
  int aBase = wv * 2048;  // (wv*32)*64
  int bBase = wv * 1024;  // (wv*16)*64

#define G1_ISSUE(t) do { _Float16* Lb = lds[(t) & 1];            \
    gload16(aSrc[0] + (t) * 64, Lb + aBase);                     \
    gload16(aSrc[1] + (t) * 64, Lb + aBase + 512);               \
    gload16(aSrc[2] + (t) * 64, Lb + aBase + 1024);              \
    gload16(aSrc[3] + (t) * 64, Lb + aBase + 1536);              \
    gload16(b1Src[0] + (t) * 64, Lb + 16384 + bBase);            \
    gload16(b1Src[1] + (t) * 64, Lb + 16384 + bBase + 512);      \
    gload16(b3Src[0] + (t) * 64, Lb + 24576 + bBase);            \
    gload16(b3Src[1] + (t) * 64, Lb + 24576 + bBase + 512);      \
  } while (0)

  f32x4 acc1[4][4], acc3[4][4];
  f32x4 zero = {0.f, 0.f, 0.f, 0.f};
#pragma unroll
  for (int i = 0; i < 4; i++)
#pragma unroll
    for (int j = 0; j < 4; j++) { acc1[i][j] = zero; acc3[i][j] = zero; }

  int l15 = lane & 15, qv = lane >> 4, x7 = l15 & 7;
  int wm = (wv >> 1) * 64, wn = (wv & 1) * 64;

  G1_ISSUE(0);
  G1_ISSUE(1);
  for (int t = 0; t < DDIM / 64; t++) {
    if (t < DDIM / 64 - 1) asm volatile("s_waitcnt vmcnt(8)" ::: "memory");
    else                   asm volatile("s_waitcnt vmcnt(0)" ::: "memory");
    __builtin_amdgcn_s_barrier();
    asm volatile("" ::: "memory");
    __builtin_amdgcn_sched_barrier(0);
    const _Float16* L = lds[t & 1];
#pragma unroll
    for (int kk = 0; kk < 2; kk++) {
      int pc = (kk * 4 + qv) ^ x7;
      f16x8 af[4], b1f[4];
#pragma unroll
      for (int i = 0; i < 4; i++)
        af[i] = *(const f16x8*)&L[(wm + i * 16 + l15) * 64 + pc * 8];
#pragma unroll
      for (int j = 0; j < 4; j++)
        b1f[j] = *(const f16x8*)&L[16384 + (wn + j * 16 + l15) * 64 + pc * 8];
      __builtin_amdgcn_s_setprio(1);
#pragma unroll
      for (int i = 0; i < 4; i++)
#pragma unroll
        for (int j = 0; j < 4; j++)
          acc1[i][j] = __builtin_amdgcn_mfma_f32_16x16x32_f16(af[i], b1f[j], acc1[i][j], 0, 0, 0);
      __builtin_amdgcn_s_setprio(0);
      f16x8 b3f[4];
#pragma unroll
      for (int j = 0; j < 4; j++)
        b3f[j] = *(const f16x8*)&L[24576 + (wn + j * 16 + l15) * 64 + pc * 8];
      __builtin_amdgcn_s_setprio(1);
#pragma unroll
      for (int i = 0; i < 4; i++)
#pragma unroll
        for (int j = 0; j < 4; j++)
          acc3[i][j] = __builtin_amdgcn_mfma_f32_16x16x32_f16(af[i], b3f[j], acc3[i][j], 0, 0, 0);
      __builtin_amdgcn_s_setprio(0);
    }
    __builtin_amdgcn_s_barrier();
    asm volatile("" ::: "memory");
    if (t + 2 < DDIM / 64) { G1_ISSUE(t + 2); }
  }
#undef G1_ISSUE

  int q4 = qv * 4;
#pragma unroll
  for (int i = 0; i < 4; i++) {
#pragma unroll
    for (int r = 0; r < 4; r++) {
      int row = rt * 256 + wm + i * 16 + q4 + r;
      if (row >= cnt) continue;
      _Float16* hrow = h + (size_t)(off + row) * FDIM + (size_t)ct * 128 + wn;
#pragma unroll
      for (int j = 0; j < 4; j++) {
        float a = acc1[i][j][r];
        float b = acc3[i][j][r];
        float hv = (a / (1.f + __expf(-a))) * b;
        hrow[j * 16 + l15] = (_Float16)hv;
      }
    }
  }
}

// ---------------- GEMM2: part[slot] = w * (h[slot] @ w2[e]) -- no atomics ----------------
// Tile 128x128, 256 threads = 4 waves (2M x 2N), wave owns 64x64.
// Same counted-vmcnt double-buffer pipeline, NK = 3584/64 = 56.
__global__ __launch_bounds__(256, 2) void gemm2_kernel(
    const _Float16* __restrict__ h, const _Float16* __restrict__ w2t,
    const int* __restrict__ counts, const int* __restrict__ offsets,
    const float* __restrict__ tok_w, const int* __restrict__ sched,
    _Float16* __restrict__ part) {
  int sc = sched[blockIdx.y];
  if (sc < 0) return;
  int e = sc >> 16, rt = sc & 0xFFFF;
  int cnt = counts[e];
  int ct = blockIdx.x;
  int off = offsets[e];

  // per buffer: A 128x64 (8192 f16) | B 128x64 (8192)
  __shared__ _Float16 lds[2][16384];

  int tid = threadIdx.x, lane = tid & 63, wv = tid >> 6;
  int p = lane & 7, rsub = lane >> 3, c = p ^ rsub;

  const _Float16 *aSrc[4], *bSrc[4];
#pragma unroll
  for (int g = 0; g < 4; g++) {
    int r = wv * 32 + g * 8 + rsub;
    aSrc[g] = h + (size_t)(off + rt * 128 + r) * FDIM + c * 8;
    bSrc[g] = w2t + ((size_t)e * DDIM + (size_t)ct * 128 + r) * FDIM + c * 8;
  }
  int abBase = wv * 2048;

#define G2_ISSUE(t) do { _Float16* Lb = lds[(t) & 1];            \
    gload16(aSrc[0] + (t) * 64, Lb + abBase);                    \
    gload16(aSrc[1] + (t) * 64, Lb + abBase + 512);              \
    gload16(aSrc[2] + (t) * 64, Lb + abBase + 1024);             \
    gload16(aSrc[3] + (t) * 64, Lb + abBase + 1536);             \
    gload16(bSrc[0] + (t) * 64, Lb + 8192 + abBase);             \
    gload16(bSrc[1] + (t) * 64, Lb + 8192 + abBase + 512);       \
    gload16(bSrc[2] + (t) * 64, Lb + 8192 + abBase + 1024);      \
    gload16(bSrc[3] + (t) * 64, Lb + 8192 + abBase + 1536);      \
  } while (0)

  f32x4 acc[4][4];
  f32x4 zero = {0.f, 0.f, 0.f, 0.f};
#pragma unroll
  for (int i = 0; i < 4; i++)
#pragma unroll
    for (int j = 0; j < 4; j++) acc[i][j] = zero;

  int l15 = lane & 15, qv = lane >> 4, x7 = l15 & 7;
  int wm = (wv >> 1) * 64, wn = (wv & 1) * 64;

  G2_ISSUE(0);
  G2_ISSUE(1);
  for (int t = 0; t < FDIM / 64; t++) {
    if (t < FDIM / 64 - 1) asm volatile("s_waitcnt vmcnt(8)" ::: "memory");
    else                   asm volatile("s_waitcnt vmcnt(0)" ::: "memory");
    __builtin_amdgcn_s_barrier();
    asm volatile("" ::: "memory");
    __builtin_amdgcn_sched_barrier(0);
    const _Float16* L = lds[t & 1];
#pragma unroll
    for (int kk = 0; kk < 2; kk++) {
      int pc = (kk * 4 + qv) ^ x7;
      f16x8 af[4], bf[4];
#pragma unroll
      for (int i = 0; i < 4; i++)
        af[i] = *(const f16x8*)&L[(wm + i * 16 + l15) * 64 + pc * 8];
#pragma unroll
      for (int j = 0; j < 4; j++)
        bf[j] = *(const f16x8*)&L[8192 + (wn + j * 16 + l15) * 64 + pc * 8];
      __builtin_amdgcn_s_setprio(1);
#pragma unroll
      for (int i = 0; i < 4; i++)
#pragma unroll
        for (int j = 0; j < 4; j++)
          acc[i][j] = __builtin_amdgcn_mfma_f32_16x16x32_f16(af[i], bf[j], acc[i][j], 0, 0, 0);
      __builtin_amdgcn_s_setprio(0);
    }
    __builtin_amdgcn_s_barrier();
    asm volatile("" ::: "memory");
    if (t + 2 < FDIM / 64) { G2_ISSUE(t + 2); }
  }
#undef G2_ISSUE

  int q4 = qv * 4;
#pragma unroll
  for (int i = 0; i < 4; i++) {
#pragma unroll
    for (int r = 0; r < 4; r++) {
      int row = rt * 128 + wm + i * 16 + q4 + r;
      if (row >= cnt) continue;
      float wgt = tok_w[e * T_TOKENS + row];
      _Float16* prow = part + (size_t)(off + row) * DDIM + (size_t)ct * 128 + wn;
#pragma unroll
      for (int j = 0; j < 4; j++)
        prow[j * 16 + l15] = (_Float16)(acc[i][j][r] * wgt);
    }
  }
}

// ---------------- gather: out[t] = part[slotA(t)] + part[slotB(t)] ----------------
__global__ __launch_bounds__(256) void gather_kernel(
    const _Float16* __restrict__ part, const int2* __restrict__ tok_ref,
    const int* __restrict__ offsets, float* __restrict__ out) {
  int i = blockIdx.x * 256 + threadIdx.x;
  int t = i >> 7;            // 128 chunks of 8 per token
  int dc = (i & 127) * 8;
  int2 ref = tok_ref[t];
  int sa = offsets[ref.x >> 13] + (ref.x & 8191);
  int sb = offsets[ref.y >> 13] + (ref.y & 8191);
  f16x8 pa = *(const f16x8*)(part + (size_t)sa * DDIM + dc);
  f16x8 pb = *(const f16x8*)(part + (size_t)sb * DDIM + dc);
  float* dst = out + (size_t)t * DDIM + dc;
#pragma unroll
  for (int j = 0; j < 8; j++) dst[j] = (float)pa[j] + (float)pb[j];
}

// Workspace layout (MiB offsets; high-water ~= 338 MiB):
//   0: counts/offsets/sched1/sched2/tok_idx/tok_w/tok_ref (<1 MiB)
//   1: xh 16 | 17: w1t 56 | 73: w3t 56 | 129: w2t 56 | 185: h 118.4 | 304: part 33.6
extern "C" void kernel_launch(void* const* d_in, const int* in_sizes, int n_in,
                              void* d_out, int out_size, void* d_ws, size_t ws_size,
                              hipStream_t stream) {
  const float* x  = (const float*)d_in[0];
  const float* gw = (const float*)d_in[1];
  const float* w1 = (const float*)d_in[2];
  const float* w3 = (const float*)d_in[3];
  const float* w2 = (const float*)d_in[4];
  float* out = (float*)d_out;
  float* logits = out + (size_t)T_TOKENS * DDIM;

  char* ws = (char*)d_ws;
  const size_t MB = 1024 * 1024;
  int* counts  = (int*)ws;
  int* offsets = (int*)(ws + 64);
  int* sched1  = (int*)(ws + 128);               // 72 ints
  int* sched2  = (int*)(ws + 512);               // 136 ints
  int* tok_idx = (int*)(ws + 2048);              // 256 KB
  float* tok_w = (float*)(ws + 2048 + 262144);   // 256 KB
  int2* tok_ref = (int2*)(ws + 2048 + 2 * 262144);  // 64 KB
  _Float16* xh  = (_Float16*)(ws + 1 * MB);
  _Float16* w1t = (_Float16*)(ws + 17 * MB);
  _Float16* w3t = (_Float16*)(ws + 73 * MB);
  _Float16* w2t = (_Float16*)(ws + 129 * MB);
  _Float16* h   = (_Float16*)(ws + 185 * MB);
  _Float16* part = (_Float16*)(ws + 304 * MB);

  hipMemsetAsync(counts, 0, 256, stream);

  router_kernel<<<T_TOKENS / 4, 256, 0, stream>>>(x, gw, logits, counts, tok_idx, tok_w, tok_ref, xh);
  prefix_kernel<<<1, 64, 0, stream>>>(counts, offsets, sched1, sched2);

  transpose_f16_kernel<<<dim3(FDIM / 64, DDIM / 64, NEXP), 256, 0, stream>>>(w1, w1t, DDIM, FDIM);
  transpose_f16_kernel<<<dim3(FDIM / 64, DDIM / 64, NEXP), 256, 0, stream>>>(w3, w3t, DDIM, FDIM);
  transpose_f16_kernel<<<dim3(DDIM / 64, FDIM / 64, NEXP), 256, 0, stream>>>(w2, w2t, FDIM, DDIM);

  gemm1_kernel<<<dim3(FDIM / 128, MAXT1), 512, 0, stream>>>(xh, w1t, w3t, counts, offsets, tok_idx, sched1, h);
  gemm2_kernel<<<dim3(DDIM / 128, MAXT2), 256, 0, stream>>>(h, w2t, counts, offsets, tok_w, sched2, part);
  gather_kernel<<<T_TOKENS * DDIM / 8 / 256, 256, 0, stream>>>(part, tok_ref, offsets, out);
}

// Round 2
// 1012.484 us; speedup vs baseline: 1.1246x; 1.0212x over previous
//
#include <hip/hip_runtime.h>
#include <stdint.h>

#define T_TOKENS 8192
#define DDIM 1024
#define FDIM 3584
#define NEXP 8

#define MAXT1 72    // 256-row tiles: 16384/256 + 8
#define MAXT2 136   // 128-row tiles: 16384/128 + 8

typedef _Float16 f16x8 __attribute__((ext_vector_type(8)));
typedef float f32x4 __attribute__((ext_vector_type(4)));

__device__ __forceinline__ void gload16(const void* g, void* l) {
  __builtin_amdgcn_global_load_lds(
      (const __attribute__((address_space(1))) void*)g,
      (__attribute__((address_space(3))) void*)l, 16, 0, 0);
}

#define FENCE asm volatile("" ::: "memory")
#define BARRIER do { FENCE; __builtin_amdgcn_s_barrier(); FENCE; } while (0)

// One compute phase of the template: read A-quad q (2 m-frags x 2 kk),
// optional extra work (B preload or staging) in the same window, then
// barrier -> setprio(1) -> 16 MFMA -> setprio(0) -> barrier.
// Resolves LA/wm/l15/pc0/pc1/bf/acc from the enclosing scope.
#define GPHASE(q, ...) {                                                                                     \
    f16x8 a0  = *(const f16x8*)&LA[(wm + ((q) * 2)     * 16 + l15) * 64 + pc0];                              \
    f16x8 a0k = *(const f16x8*)&LA[(wm + ((q) * 2)     * 16 + l15) * 64 + pc1];                              \
    f16x8 a1  = *(const f16x8*)&LA[(wm + ((q) * 2 + 1) * 16 + l15) * 64 + pc0];                              \
    f16x8 a1k = *(const f16x8*)&LA[(wm + ((q) * 2 + 1) * 16 + l15) * 64 + pc1];                              \
    __VA_ARGS__;                                                                                             \
    BARRIER;                                                                                                 \
    __builtin_amdgcn_s_setprio(1);                                                                           \
    _Pragma("unroll")                                                                                        \
    for (int j = 0; j < 4; j++) {                                                                            \
      acc[(q) * 2][j]     = __builtin_amdgcn_mfma_f32_16x16x32_f16(a0,  bf[0][j], acc[(q) * 2][j], 0, 0, 0); \
      acc[(q) * 2 + 1][j] = __builtin_amdgcn_mfma_f32_16x16x32_f16(a1,  bf[0][j], acc[(q) * 2 + 1][j], 0, 0, 0); \
    }                                                                                                        \
    _Pragma("unroll")                                                                                        \
    for (int j = 0; j < 4; j++) {                                                                            \
      acc[(q) * 2][j]     = __builtin_amdgcn_mfma_f32_16x16x32_f16(a0k, bf[1][j], acc[(q) * 2][j], 0, 0, 0); \
      acc[(q) * 2 + 1][j] = __builtin_amdgcn_mfma_f32_16x16x32_f16(a1k, bf[1][j], acc[(q) * 2 + 1][j], 0, 0, 0); \
    }                                                                                                        \
    __builtin_amdgcn_s_setprio(0);                                                                           \
    BARRIER;                                                                                                 \
  }

// ---------------- router: logits, softmax, top-2, expert lists; also emits xh=f16(x) ----
__global__ __launch_bounds__(256) void router_kernel(
    const float* __restrict__ x, const float* __restrict__ gw,
    float* __restrict__ logits_out, int* __restrict__ counts,
    int* __restrict__ tok_idx, float* __restrict__ tok_w,
    int2* __restrict__ tok_ref, _Float16* __restrict__ xh) {
  int t = blockIdx.x * 4 + (threadIdx.x >> 6);  // one wave per token
  int lane = threadIdx.x & 63;
  const float* xr = x + (size_t)t * DDIM;
  float acc[NEXP];
#pragma unroll
  for (int e = 0; e < NEXP; e++) acc[e] = 0.f;
  for (int c = 0; c < DDIM / 64; c++) {
    float xv = xr[c * 64 + lane];
    xh[(size_t)t * DDIM + c * 64 + lane] = (_Float16)xv;
#pragma unroll
    for (int e = 0; e < NEXP; e++) acc[e] += xv * gw[e * DDIM + c * 64 + lane];
  }
#pragma unroll
  for (int e = 0; e < NEXP; e++) {
    for (int off = 32; off > 0; off >>= 1) acc[e] += __shfl_xor(acc[e], off, 64);
  }
  if (lane == 0) {
    float m = acc[0];
    for (int e = 1; e < NEXP; e++) m = fmaxf(m, acc[e]);
    float p[NEXP];
    for (int e = 0; e < NEXP; e++) p[e] = expf(acc[e] - m);
    int e1 = 0;
    for (int e = 1; e < NEXP; e++) if (p[e] > p[e1]) e1 = e;  // strict > : lowest idx on tie
    int e2 = (e1 == 0) ? 1 : 0;
    for (int e = 0; e < NEXP; e++) { if (e == e1) continue; if (p[e] > p[e2]) e2 = e; }
    float wsum = p[e1] + p[e2];
    float w1v = p[e1] / wsum, w2v = p[e2] / wsum;
    for (int e = 0; e < NEXP; e++) logits_out[(size_t)t * NEXP + e] = acc[e];
    int pos1 = atomicAdd(&counts[e1], 1);
    tok_idx[e1 * T_TOKENS + pos1] = t; tok_w[e1 * T_TOKENS + pos1] = w1v;
    int pos2 = atomicAdd(&counts[e2], 1);
    tok_idx[e2 * T_TOKENS + pos2] = t; tok_w[e2 * T_TOKENS + pos2] = w2v;
    tok_ref[t] = make_int2((e1 << 13) | pos1, (e2 << 13) | pos2);
  }
}

// ---------------- prefix + compact tile schedules (256-row for gemm1, 128-row for gemm2) ----
__global__ void prefix_kernel(const int* __restrict__ counts, int* __restrict__ offsets,
                              int* __restrict__ sched1, int* __restrict__ sched2) {
  if (threadIdx.x == 0) {
    int s = 0, n1 = 0, n2 = 0;
    for (int e = 0; e < NEXP; e++) {
      offsets[e] = s;
      int cc = counts[e];
      int nt1 = (cc + 255) / 256;
      for (int i = 0; i < nt1; i++) sched1[n1++] = (e << 16) | i;
      int nt2 = (cc + 127) / 128;
      for (int i = 0; i < nt2; i++) sched2[n2++] = (e << 16) | i;
      s += cc;
    }
    offsets[NEXP] = s;
    for (; n1 < MAXT1; n1++) sched1[n1] = -1;
    for (; n2 < MAXT2; n2++) sched2[n2] = -1;
  }
}

// ---------------- transpose+convert: in[e][R][C] fp32 -> out[e][C][R] f16 ----------------
__global__ __launch_bounds__(256) void transpose_f16_kernel(
    const float* __restrict__ in, _Float16* __restrict__ out, int R, int C) {
  __shared__ _Float16 lt[64][72];
  size_t esz = (size_t)R * C;
  in += (size_t)blockIdx.z * esz;
  out += (size_t)blockIdx.z * esz;
  int r0 = blockIdx.y * 64, c0 = blockIdx.x * 64;
  int t = threadIdx.x;
  int r = t & 63, q = t >> 6;
  const float* src = in + (size_t)(r0 + r) * C + c0 + q * 16;
  float4 v0 = ((const float4*)src)[0];
  float4 v1 = ((const float4*)src)[1];
  float4 v2 = ((const float4*)src)[2];
  float4 v3 = ((const float4*)src)[3];
  _Float16 f[16] = {
      (_Float16)v0.x, (_Float16)v0.y, (_Float16)v0.z, (_Float16)v0.w,
      (_Float16)v1.x, (_Float16)v1.y, (_Float16)v1.z, (_Float16)v1.w,
      (_Float16)v2.x, (_Float16)v2.y, (_Float16)v2.z, (_Float16)v2.w,
      (_Float16)v3.x, (_Float16)v3.y, (_Float16)v3.z, (_Float16)v3.w};
#pragma unroll
  for (int j = 0; j < 16; j++) lt[q * 16 + j][r] = f[j];
  __syncthreads();
  _Float16* dst = out + (size_t)(c0 + r) * R + r0 + q * 16;
  *(f16x8*)dst       = *(const f16x8*)&lt[r][q * 16];
  *(f16x8*)(dst + 8) = *(const f16x8*)&lt[r][q * 16 + 8];
}

// ---------------- GEMM1: h = silu(x@w1) * (x@w3), gathered rows ----------------
// 256 rows x (128 w1-cols + 128 w3-cols) per block. B-tile rows n in [0,256):
// group g=n>>6 (32-col group), sel=(n>>5)&1 (0=w1,1=w3), col = ct*128+g*32+(n&31).
// Wave wc owns B rows wc*64..+63 => frags j=0,1 are w1 cols, j=2,3 the SAME w3
// cols => silu fusion is lane-local. 8 waves 2Mx4N, BK=64, 4 phases/K-step,
// B frags preloaded to regs in phase 0. Staging spread into phase windows
// (region consumed + closing barrier => race-free); 8 issues/wave/K-step,
// vmcnt(8) at top, never drained in main loop.
__global__ __launch_bounds__(512, 2) void gemm1_kernel(
    const _Float16* __restrict__ xh, const _Float16* __restrict__ w1t,
    const _Float16* __restrict__ w3t, const int* __restrict__ counts,
    const int* __restrict__ offsets, const int* __restrict__ tok_idx,
    const int* __restrict__ sched, _Float16* __restrict__ h) {
  int sc = sched[blockIdx.y];
  if (sc < 0) return;
  int e = sc >> 16, rt = sc & 0xFFFF;
  int cnt = counts[e];
  int ct = blockIdx.x;
  int off = offsets[e];

  // per buffer: A 256x64 (16384 f16) | B 256x64 (16384 f16)
  __shared__ _Float16 lds[2][32768];

  int tid = threadIdx.x, lane = tid & 63, wv = tid >> 6;
  int rsub = lane >> 3, p8 = lane & 7, cch = p8 ^ rsub;  // XOR-chunk swizzle (0 conflicts, measured)

  // A staging rows: wave wv covers quarter (wv>>1) of half (wv&1) -> consumed at phase wv>>1
  int R0 = (wv & 1) * 128 + (wv >> 1) * 32;
  const _Float16* aS[4];
#pragma unroll
  for (int g = 0; g < 4; g++) {
    int ir = rt * 256 + R0 + g * 8 + rsub;
    if (ir >= cnt) ir = cnt - 1;
    int tok = tok_idx[e * T_TOKENS + ir];
    aS[g] = xh + (size_t)tok * DDIM + cch * 8;
  }
  // B staging rows wv*32..+31: sel = wv&1, group = wv>>1 (constant per wave)
  const _Float16* wsel = (wv & 1) ? w3t : w1t;
  const _Float16* bS[4];
#pragma unroll
  for (int g = 0; g < 4; g++) {
    size_t row = (size_t)e * FDIM + (size_t)ct * 128 + (wv >> 1) * 32 + g * 8 + rsub;
    bS[g] = wsel + row * DDIM + cch * 8;
  }

  // prologue: stage K-tiles 0 and 1
  {
    _Float16* Lb = lds[0];
#pragma unroll
    for (int g = 0; g < 4; g++) gload16(aS[g], Lb + R0 * 64 + g * 512);
#pragma unroll
    for (int g = 0; g < 4; g++) gload16(bS[g], Lb + 16384 + wv * 2048 + g * 512);
  }
  {
    _Float16* Lb = lds[1];
#pragma unroll
    for (int g = 0; g < 4; g++) gload16(aS[g] + 64, Lb + R0 * 64 + g * 512);
#pragma unroll
    for (int g = 0; g < 4; g++) gload16(bS[g] + 64, Lb + 16384 + wv * 2048 + g * 512);
  }
#pragma unroll
  for (int g = 0; g < 4; g++) { aS[g] += 128; bS[g] += 128; }

  f32x4 acc[8][4];
  f32x4 zero = {0.f, 0.f, 0.f, 0.f};
#pragma unroll
  for (int m = 0; m < 8; m++)
#pragma unroll
    for (int j = 0; j < 4; j++) acc[m][j] = zero;

  int wm = (wv >> 2) * 128, wc = wv & 3;
  int l15 = lane & 15, qv = lane >> 4, x7 = l15 & 7;
  int pc0 = (qv ^ x7) * 8, pc1 = ((4 + qv) ^ x7) * 8;
  f16x8 bf[2][4];

  for (int t = 0; t < DDIM / 64; t++) {
    if (t < DDIM / 64 - 1) asm volatile("s_waitcnt vmcnt(8)" ::: "memory");
    else                   asm volatile("s_waitcnt vmcnt(0)" ::: "memory");
    BARRIER;  // buffer for tile t ready in all waves
    const _Float16* LA = lds[t & 1];
    const _Float16* LB = LA + 16384;
    _Float16* LbA = lds[t & 1] + R0 * 64;              // stage dest, tile t+2 (same parity)
    _Float16* LbB = lds[t & 1] + 16384 + wv * 2048;
    bool pf = (t < DDIM / 64 - 2);
    // phase 0: B preload (consumed entirely here) + A quad 0
    GPHASE(0,
      _Pragma("unroll")
      for (int j = 0; j < 4; j++) bf[0][j] = *(const f16x8*)&LB[(wc * 64 + j * 16 + l15) * 64 + pc0];
      _Pragma("unroll")
      for (int j = 0; j < 4; j++) bf[1][j] = *(const f16x8*)&LB[(wc * 64 + j * 16 + l15) * 64 + pc1];
    );
    // phase 1: stage B halves 0,1 (B region consumed at phase-0 closing barrier)
    GPHASE(1, if (pf) { gload16(bS[0], LbB); gload16(bS[1], LbB + 512); });
    // phase 2: stage B halves 2,3
    GPHASE(2, if (pf) { gload16(bS[2], LbB + 1024); gload16(bS[3], LbB + 1536); });
    // phase 3: waves with A-quarter <=2 (consumed by phase-2 close) stage A 0,1
    GPHASE(3, if (pf && wv < 6) { gload16(aS[0], LbA); gload16(aS[1], LbA + 512); });
    // tail: all A quarters consumed; finish A staging (8 issues/wave total)
    if (pf) {
      if (wv < 6) { gload16(aS[2], LbA + 1024); gload16(aS[3], LbA + 1536); }
      else {
        gload16(aS[0], LbA);        gload16(aS[1], LbA + 512);
        gload16(aS[2], LbA + 1024); gload16(aS[3], LbA + 1536);
      }
    }
#pragma unroll
    for (int g = 0; g < 4; g++) { aS[g] += 64; bS[g] += 64; }
  }

  int q4 = qv * 4;
#pragma unroll
  for (int m = 0; m < 8; m++) {
#pragma unroll
    for (int r = 0; r < 4; r++) {
      int row = rt * 256 + wm + m * 16 + q4 + r;
      if (row >= cnt) continue;
      _Float16* hrow = h + (size_t)(off + row) * FDIM + (size_t)ct * 128 + wc * 32;
#pragma unroll
      for (int j = 0; j < 2; j++) {
        float a = acc[m][j][r];      // w1 frag
        float b = acc[m][j + 2][r];  // matching w3 frag, same col
        float hv = (a / (1.f + __expf(-a))) * b;
        hrow[j * 16 + l15] = (_Float16)hv;
      }
    }
  }
}

// ---------------- GEMM2: part[slot] = w * (h[slot] @ w2[e]) -- no atomics ----------------
// 128x128 tile, 4 waves 2Mx2N (wave 64x64), BK=64, 2 phases/K-step, B frags in
// regs, LDS 64KB -> 2 blocks/CU, 1088 blocks for load balance. Same counted-vmcnt
// phase pipeline: B staged in phase-1 window, A at tail, 8 issues/wave/K-step.
__global__ __launch_bounds__(256, 2) void gemm2_kernel(
    const _Float16* __restrict__ h, const _Float16* __restrict__ w2t,
    const int* __restrict__ counts, const int* __restrict__ offsets,
    const float* __restrict__ tok_w, const int* __restrict__ sched,
    _Float16* __restrict__ part) {
  int sc = sched[blockIdx.y];
  if (sc < 0) return;
  int e = sc >> 16, rt = sc & 0xFFFF;
  int cnt = counts[e];
  int ct = blockIdx.x;
  int off = offsets[e];

  // per buffer: A 128x64 (8192 f16) | B 128x64 (8192 f16)
  __shared__ _Float16 lds[2][16384];

  int tid = threadIdx.x, lane = tid & 63, wv = tid >> 6;
  int rsub = lane >> 3, p8 = lane & 7, cch = p8 ^ rsub;

  const _Float16* aS[4];
  const _Float16* bS[4];
#pragma unroll
  for (int g = 0; g < 4; g++) {
    int r = wv * 32 + g * 8 + rsub;
    aS[g] = h + (size_t)(off + rt * 128 + r) * FDIM + cch * 8;
    bS[g] = w2t + ((size_t)e * DDIM + (size_t)ct * 128 + r) * FDIM + cch * 8;
  }

  {
    _Float16* Lb = lds[0];
#pragma unroll
    for (int g = 0; g < 4; g++) gload16(aS[g], Lb + wv * 2048 + g * 512);
#pragma unroll
    for (int g = 0; g < 4; g++) gload16(bS[g], Lb + 8192 + wv * 2048 + g * 512);
  }
  {
    _Float16* Lb = lds[1];
#pragma unroll
    for (int g = 0; g < 4; g++) gload16(aS[g] + 64, Lb + wv * 2048 + g * 512);
#pragma unroll
    for (int g = 0; g < 4; g++) gload16(bS[g] + 64, Lb + 8192 + wv * 2048 + g * 512);
  }
#pragma unroll
  for (int g = 0; g < 4; g++) { aS[g] += 128; bS[g] += 128; }

  f32x4 acc[4][4];
  f32x4 zero = {0.f, 0.f, 0.f, 0.f};
#pragma unroll
  for (int m = 0; m < 4; m++)
#pragma unroll
    for (int j = 0; j < 4; j++) acc[m][j] = zero;

  int wm = (wv >> 1) * 64, wn = (wv & 1) * 64;
  int l15 = lane & 15, qv = lane >> 4, x7 = l15 & 7;
  int pc0 = (qv ^ x7) * 8, pc1 = ((4 + qv) ^ x7) * 8;
  f16x8 bf[2][4];

  for (int t = 0; t < FDIM / 64; t++) {
    if (t < FDIM / 64 - 1) asm volatile("s_waitcnt vmcnt(8)" ::: "memory");
    else                   asm volatile("s_waitcnt vmcnt(0)" ::: "memory");
    BARRIER;
    const _Float16* LA = lds[t & 1];
    const _Float16* LB = LA + 8192;
    _Float16* LbA = lds[t & 1] + wv * 2048;
    _Float16* LbB = lds[t & 1] + 8192 + wv * 2048;
    bool pf = (t < FDIM / 64 - 2);
    // phase 0: B preload + A quad 0
    GPHASE(0,
      _Pragma("unroll")
      for (int j = 0; j < 4; j++) bf[0][j] = *(const f16x8*)&LB[(wn + j * 16 + l15) * 64 + pc0];
      _Pragma("unroll")
      for (int j = 0; j < 4; j++) bf[1][j] = *(const f16x8*)&LB[(wn + j * 16 + l15) * 64 + pc1];
    );
    // phase 1: stage all B (consumed at phase-0 close)
    GPHASE(1, if (pf) {
      gload16(bS[0], LbB);        gload16(bS[1], LbB + 512);
      gload16(bS[2], LbB + 1024); gload16(bS[3], LbB + 1536);
    });
    // tail: A fully consumed (quads 0,1 across the 2 phases)
    if (pf) {
      gload16(aS[0], LbA);        gload16(aS[1], LbA + 512);
      gload16(aS[2], LbA + 1024); gload16(aS[3], LbA + 1536);
    }
#pragma unroll
    for (int g = 0; g < 4; g++) { aS[g] += 64; bS[g] += 64; }
  }

  int q4 = qv * 4;
#pragma unroll
  for (int m = 0; m < 4; m++) {
#pragma unroll
    for (int r = 0; r < 4; r++) {
      int row = rt * 128 + wm + m * 16 + q4 + r;
      if (row >= cnt) continue;
      float wgt = tok_w[e * T_TOKENS + row];
      _Float16* prow = part + (size_t)(off + row) * DDIM + (size_t)ct * 128 + wn;
#pragma unroll
      for (int j = 0; j < 4; j++)
        prow[j * 16 + l15] = (_Float16)(acc[m][j][r] * wgt);
    }
  }
}

// ---------------- gather: out[t] = part[slotA(t)] + part[slotB(t)] ----------------
__global__ __launch_bounds__(256) void gather_kernel(
    const _Float16* __restrict__ part, const int2* __restrict__ tok_ref,
    const int* __restrict__ offsets, float* __restrict__ out) {
  int i = blockIdx.x * 256 + threadIdx.x;
  int t = i >> 7;            // 128 chunks of 8 per token
  int dc = (i & 127) * 8;
  int2 ref = tok_ref[t];
  int sa = offsets[ref.x >> 13] + (ref.x & 8191);
  int sb = offsets[ref.y >> 13] + (ref.y & 8191);
  f16x8 pa = *(const f16x8*)(part + (size_t)sa * DDIM + dc);
  f16x8 pb = *(const f16x8*)(part + (size_t)sb * DDIM + dc);
  float* dst = out + (size_t)t * DDIM + dc;
#pragma unroll
  for (int j = 0; j < 8; j++) dst[j] = (float)pa[j] + (float)pb[j];
}

// Workspace layout (MiB offsets; high-water ~= 338 MiB):
//   0: counts/offsets/sched1/sched2/tok_idx/tok_w/tok_ref (<1 MiB)
//   1: xh 16 | 17: w1t 56 | 73: w3t 56 | 129: w2t 56 | 185: h 119 | 304: part 33.6
extern "C" void kernel_launch(void* const* d_in, const int* in_sizes, int n_in,
                              void* d_out, int out_size, void* d_ws, size_t ws_size,
                              hipStream_t stream) {
  const float* x  = (const float*)d_in[0];
  const float* gw = (const float*)d_in[1];
  const float* w1 = (const float*)d_in[2];
  const float* w3 = (const float*)d_in[3];
  const float* w2 = (const float*)d_in[4];
  float* out = (float*)d_out;
  float* logits = out + (size_t)T_TOKENS * DDIM;

  char* ws = (char*)d_ws;
  const size_t MB = 1024 * 1024;
  int* counts  = (int*)ws;
  int* offsets = (int*)(ws + 64);
  int* sched1  = (int*)(ws + 128);               // 72 ints
  int* sched2  = (int*)(ws + 512);               // 136 ints
  int* tok_idx = (int*)(ws + 2048);              // 256 KB
  float* tok_w = (float*)(ws + 2048 + 262144);   // 256 KB
  int2* tok_ref = (int2*)(ws + 2048 + 2 * 262144);  // 64 KB
  _Float16* xh  = (_Float16*)(ws + 1 * MB);
  _Float16* w1t = (_Float16*)(ws + 17 * MB);
  _Float16* w3t = (_Float16*)(ws + 73 * MB);
  _Float16* w2t = (_Float16*)(ws + 129 * MB);
  _Float16* h   = (_Float16*)(ws + 185 * MB);
  _Float16* part = (_Float16*)(ws + 304 * MB);

  hipMemsetAsync(counts, 0, 256, stream);

  router_kernel<<<T_TOKENS / 4, 256, 0, stream>>>(x, gw, logits, counts, tok_idx, tok_w, tok_ref, xh);
  prefix_kernel<<<1, 64, 0, stream>>>(counts, offsets, sched1, sched2);

  transpose_f16_kernel<<<dim3(FDIM / 64, DDIM / 64, NEXP), 256, 0, stream>>>(w1, w1t, DDIM, FDIM);
  transpose_f16_kernel<<<dim3(FDIM / 64, DDIM / 64, NEXP), 256, 0, stream>>>(w3, w3t, DDIM, FDIM);
  transpose_f16_kernel<<<dim3(DDIM / 64, FDIM / 64, NEXP), 256, 0, stream>>>(w2, w2t, FDIM, DDIM);

  gemm1_kernel<<<dim3(FDIM / 128, MAXT1), 512, 0, stream>>>(xh, w1t, w3t, counts, offsets, tok_idx, sched1, h);
  gemm2_kernel<<<dim3(DDIM / 128, MAXT2), 256, 0, stream>>>(h, w2t, counts, offsets, tok_w, sched2, part);
  gather_kernel<<<T_TOKENS * DDIM / 8 / 256, 256, 0, stream>>>(part, tok_ref, offsets, out);
}